// Round 8
// baseline (335.732 us; speedup 1.0000x reference)
//
#include <hip/hip_runtime.h>

#define EPS 1e-5f
typedef unsigned short u16;
typedef unsigned int u32;

typedef __attribute__((ext_vector_type(8))) short bf16x8;
typedef __attribute__((ext_vector_type(4))) short bf16x4;
typedef __attribute__((ext_vector_type(4))) float f32x4;

// ---------- bf16 helpers ----------
__device__ __forceinline__ float bf2f(u16 h) {
    u32 u = ((u32)h) << 16;
    return __builtin_bit_cast(float, u);
}
__device__ __forceinline__ u16 f2bf(float f) {
    u32 u = __builtin_bit_cast(u32, f);
    u32 r = (u + 0x7fffu + ((u >> 16) & 1u)) >> 16;   // RNE
    return (u16)r;
}
__device__ __forceinline__ u32 pack2(float a, float b) {
    return (u32)f2bf(a) | ((u32)f2bf(b) << 16);
}
// extract packed bf16 pair from a u32 word, pure register bit-ops
__device__ __forceinline__ float bflo(u32 u) {
    return __builtin_bit_cast(float, u << 16);
}
__device__ __forceinline__ float bfhi(u32 u) {
    return __builtin_bit_cast(float, u & 0xffff0000u);
}

// ============================================================
// K1: qkv[n,o,l] = sum_c W[o,c] * x[b,c,h,l]   (n = b*64+h)
// ============================================================
__global__ __launch_bounds__(256) void k1_gemm_qkv(
    const float* __restrict__ x, const float* __restrict__ Wq,
    float* __restrict__ qkv, float* __restrict__ stats)
{
    __shared__ float Wt[64 * 68];
    __shared__ float xt[64 * 128];
    const int tid = threadIdx.x;
    const int ot = blockIdx.x;
    const int n  = blockIdx.y;
    const int b = n >> 6, h = n & 63;
    const int to = tid >> 5, tl = tid & 31;
    const int o0 = to * 8, l0 = tl * 4;

    float acc[8][4];
#pragma unroll
    for (int r = 0; r < 8; ++r) { acc[r][0]=0.f; acc[r][1]=0.f; acc[r][2]=0.f; acc[r][3]=0.f; }

    for (int cb = 0; cb < 128; cb += 64) {
        __syncthreads();
#pragma unroll
        for (int k = 0; k < 4; ++k) {
            int f = tid + k * 256;
            int oo = f >> 4, c4 = f & 15;
            float4 v = *(const float4*)(Wq + (ot * 64 + oo) * 128 + cb + c4 * 4);
            *(float4*)(Wt + oo * 68 + c4 * 4) = v;
        }
#pragma unroll
        for (int k = 0; k < 8; ++k) {
            int f = tid + k * 256;
            int c = f >> 5, l4 = f & 31;
            float4 v = *(const float4*)(x + ((size_t)((b * 128 + cb + c) * 64 + h)) * 128 + l4 * 4);
            *(float4*)(xt + c * 128 + l4 * 4) = v;
        }
        __syncthreads();
#pragma unroll 4
        for (int c = 0; c < 64; ++c) {
            float4 xv = *(const float4*)(xt + c * 128 + l0);
#pragma unroll
            for (int r = 0; r < 8; ++r) {
                float w = Wt[(o0 + r) * 68 + c];
                acc[r][0] += w * xv.x; acc[r][1] += w * xv.y;
                acc[r][2] += w * xv.z; acc[r][3] += w * xv.w;
            }
        }
    }

#pragma unroll
    for (int r = 0; r < 8; ++r) {
        int o = ot * 64 + o0 + r;
        *(float4*)(qkv + ((size_t)n * 256 + o) * 128 + l0) =
            make_float4(acc[r][0], acc[r][1], acc[r][2], acc[r][3]);
        float s  = acc[r][0] + acc[r][1] + acc[r][2] + acc[r][3];
        float sq = acc[r][0]*acc[r][0] + acc[r][1]*acc[r][1] + acc[r][2]*acc[r][2] + acc[r][3]*acc[r][3];
#pragma unroll
        for (int m = 1; m < 32; m <<= 1) {
            s  += __shfl_xor(s, m);
            sq += __shfl_xor(sq, m);
        }
        if (tl == 0) {
            atomicAdd(&stats[o], s);
            atomicAdd(&stats[256 + o], sq);
        }
    }
}

__global__ void k3_coef_qkv(const float* __restrict__ stats,
                            const float* __restrict__ gamma, const float* __restrict__ beta,
                            float* __restrict__ coef)
{
    int o = threadIdx.x;
    const float cnt = 16384.f;
    float mean = stats[o] / cnt;
    float var  = stats[256 + o] / cnt - mean * mean;
    float a = gamma[o] * rsqrtf(var + EPS);
    coef[o] = a;
    coef[256 + o] = beta[o] - a * mean;
}

// ============================================================
// K4 v3 (pass 1): unchanged compute. Writer epilogue: qk stored
// in [jc][row][16] blocks (jc = 16-col chunk) so K6's per-jc wave
// read is a contiguous span.
// ============================================================
__global__ __launch_bounds__(512, 4) void k4_pass1(
    const float* __restrict__ qkv, const float* __restrict__ rel,
    const float* __restrict__ cq, u16* __restrict__ qk,
    float* __restrict__ stats)
{
    __shared__ u16 QEb[128 * 136];
    __shared__ u16 KEb[128 * 136];
    __shared__ float red[8 * 6];
    const int tid = threadIdx.x;
    const int n = blockIdx.x >> 4, g = blockIdx.x & 15;

    const int pt = tid & 31, pi = tid >> 5;
    const int t0 = pt * 4, i0 = pi * 8;
    const int d0 = t0 - i0 + 120;

    float qes = 0.f, qesq = 0.f, kes = 0.f, kesq = 0.f;

#pragma unroll
    for (int mat = 0; mat < 2; ++mat) {
        float qv[4][4];
#pragma unroll
        for (int c = 0; c < 4; ++c) {
            int o = g * 16 + mat * 4 + c;
            float a = cq[o], bb = cq[256 + o];
            float4 x0 = *(const float4*)(qkv + ((size_t)n * 256 + o) * 128 + t0);
            qv[c][0] = fmaf(a, x0.x, bb); qv[c][1] = fmaf(a, x0.y, bb);
            qv[c][2] = fmaf(a, x0.z, bb); qv[c][3] = fmaf(a, x0.w, bb);
        }
        float rr[4][12];
#pragma unroll
        for (int c = 0; c < 4; ++c) {
            const float* p = rel + (mat * 4 + c) * 255 + d0;
#pragma unroll
            for (int j = 0; j < 3; ++j) {
                float4 v = *(const float4*)(p + j * 4);
                rr[c][j*4+0] = v.x; rr[c][j*4+1] = v.y;
                rr[c][j*4+2] = v.z; rr[c][j*4+3] = v.w;
            }
        }
        u16* MB = mat ? KEb : QEb;
        float s = 0.f, sq = 0.f;
#pragma unroll
        for (int ii = 0; ii < 8; ++ii) {
            float vv[4];
#pragma unroll
            for (int tt = 0; tt < 4; ++tt) {
                int dl = tt - ii + 7;
                float v = qv[0][tt] * rr[0][dl] + qv[1][tt] * rr[1][dl]
                        + qv[2][tt] * rr[2][dl] + qv[3][tt] * rr[3][dl];
                vv[tt] = v;
                s += v; sq = fmaf(v, v, sq);
            }
            *(uint2*)(MB + (i0 + ii) * 136 + t0) =
                make_uint2(pack2(vv[0], vv[1]), pack2(vv[2], vv[3]));
        }
        if (mat == 0) { qes = s; qesq = sq; } else { kes = s; kesq = sq; }
    }
    __syncthreads();

    const int lane = tid & 63, wv = tid >> 6;
    const int fm = lane & 15, fq = lane >> 4;

    f32x4 acc[8];
#pragma unroll
    for (int tj = 0; tj < 8; ++tj) acc[tj] = (f32x4){0.f, 0.f, 0.f, 0.f};

#pragma unroll
    for (int kb = 0; kb < 4; ++kb) {
        const int ko = kb * 32 + fq * 8;
        bf16x8 a0 = *(const bf16x8*)(QEb + (wv * 16 + fm) * 136 + ko);
#pragma unroll
        for (int tj = 0; tj < 8; ++tj) {
            bf16x8 bfr = *(const bf16x8*)(KEb + (tj * 16 + fm) * 136 + ko);
            acc[tj] = __builtin_amdgcn_mfma_f32_16x16x32_bf16(a0, bfr, acc[tj], 0, 0, 0);
        }
    }

    float qks = 0.f, qksq = 0.f;
#pragma unroll
    for (int tj = 0; tj < 8; ++tj) {
#pragma unroll
        for (int r = 0; r < 4; ++r) {
            float v = acc[tj][r];
            qks += v; qksq = fmaf(v, v, qksq);
            QEb[(wv * 16 + fq * 4 + r) * 136 + tj * 16 + fm] = f2bf(v);
        }
    }

#pragma unroll
    for (int m = 1; m < 64; m <<= 1) {
        qes += __shfl_xor(qes, m);  qesq += __shfl_xor(qesq, m);
        kes += __shfl_xor(kes, m);  kesq += __shfl_xor(kesq, m);
        qks += __shfl_xor(qks, m);  qksq += __shfl_xor(qksq, m);
    }
    if (lane == 0) {
        red[wv * 6 + 0] = qes; red[wv * 6 + 1] = qesq;
        red[wv * 6 + 2] = kes; red[wv * 6 + 3] = kesq;
        red[wv * 6 + 4] = qks; red[wv * 6 + 5] = qksq;
    }
    __syncthreads();

    u16* qkg = qk + (size_t)(n * 16 + g) * 16384;
#pragma unroll
    for (int k = 0; k < 4; ++k) {
        int f = tid + k * 512;
        int row = f >> 4, c8 = f & 15;
        uint4 v = *(const uint4*)(QEb + row * 136 + c8 * 8);
        *(uint4*)(qkg + ((c8 >> 1) * 128 + row) * 16 + (c8 & 1) * 8) = v;
    }

    if (tid < 6) {
        float tot = 0.f;
#pragma unroll
        for (int w = 0; w < 8; ++w) tot += red[w * 6 + tid];
        int off = (tid & 1) ? 560 : 512;
        int ch = (tid < 2) ? (16 + g) : (tid < 4) ? (32 + g) : g;
        atomicAdd(&stats[off + ch], tot);
    }
}

__global__ void k5_coef_sim(const float* __restrict__ stats,
                            const float* __restrict__ gamma, const float* __restrict__ beta,
                            float* __restrict__ coef)
{
    int ch = threadIdx.x;
    if (ch < 48) {
        const float cnt = 2097152.f;
        float mean = stats[512 + ch] / cnt;
        float var  = stats[560 + ch] / cnt - mean * mean;
        float a = gamma[ch] * rsqrtf(var + EPS);
        coef[ch] = a;
        coef[48 + ch] = beta[ch] - a * mean;
    }
}

// ============================================================
// K6 v16 (pass 2): v15's channel-split body + FORCED 2-STEP
// PIPELINE under an adequate register budget.
// Evidence chain: v15 proved the compiler chooses 28 VGPR (~2
// loads in flight) even with a >=256 budget -- its scheduler
// won't batch; ~46% of k6 remains exposed dependency stall.
// v11 proved the named-set+sched_barrier mechanism compiles and
// runs; it spilled because its need (~100 VGPR) exceeded its
// budget (~64). v16: need ~80 (4-ch body: 16 regs/set), budget
// >=256 via (128,2), 128-thr blocks (the never-spilled config).
// All LDS addresses = per-thread base + compile-time immediate.
// Micro-opt: log2e folded into aqk/aqe/ake, exp2f instead of
// __expf (-1 VALU/step).
// Diagnostics: VGPR must rise to ~70-100; FETCH/WRITE must stay
// ~78/20 MB (else spill -> revert).
// ============================================================
#define K6_STEP(rb, rv, vv, qkf)                                             \
    {                                                                        \
        float qe = q0 * bf2f((u16)rb[0]) + q1 * bf2f((u16)rb[1])             \
                 + q2 * bf2f((u16)rb[2]) + q3 * bf2f((u16)rb[3]);            \
        float ke = k0 * bf2f((u16)rb[4]) + k1 * bf2f((u16)rb[5])             \
                 + k2 * bf2f((u16)rb[6]) + k3 * bf2f((u16)rb[7]);            \
        float s = fmaf(aqk, (qkf), qe + ke);                                 \
        float e = exp2f(s);                                                  \
        l += e;                                                              \
        am[0] = fmaf(e, bf2f((u16)vv[0]), am[0]);                            \
        am[1] = fmaf(e, bf2f((u16)vv[1]), am[1]);                            \
        am[2] = fmaf(e, bf2f((u16)vv[2]), am[2]);                            \
        am[3] = fmaf(e, bf2f((u16)vv[3]), am[3]);                            \
        ame[0] = fmaf(e, bf2f((u16)rv[0]), ame[0]);                          \
        ame[1] = fmaf(e, bf2f((u16)rv[1]), ame[1]);                          \
        ame[2] = fmaf(e, bf2f((u16)rv[2]), ame[2]);                          \
        ame[3] = fmaf(e, bf2f((u16)rv[3]), ame[3]);                          \
    }

// load unit u (steps 2u, 2u+1) into register set S.
// prb = rbq + i*8, prv = rvb + i*4 (u16 units); row d = i+127-m ->
// offsets (127-2u)*{8,4} etc. -- all compile-time immediates >= 0.
#define K6_LOADU(S, u)                                                       \
    {                                                                        \
        S##rbe = *(const bf16x8*)(prb + (127 - 2 * (u)) * 8);                \
        S##rbo = *(const bf16x8*)(prb + (126 - 2 * (u)) * 8);                \
        S##rve = *(const bf16x4*)(prv + (127 - 2 * (u)) * 4);                \
        S##rvo = *(const bf16x4*)(prv + (126 - 2 * (u)) * 4);                \
        S##vve = *(const bf16x4*)(vb + (2 * (u)) * 4);                       \
        S##vvo = *(const bf16x4*)(vb + (2 * (u) + 1) * 4);                   \
    }

// one pipeline unit: issue loads for u+1 into NS, fence, compute u from CS.
// wrd = packed qk u32 (lo = step 2u, hi = step 2u+1).
#define K6_UNIT(CS, NS, u, wrd)                                              \
    {                                                                        \
        if ((u) < 63) { K6_LOADU(NS, (u) + 1); }                             \
        __builtin_amdgcn_sched_barrier(0);                                   \
        K6_STEP(CS##rbe, CS##rve, CS##vve, bflo(wrd));                       \
        K6_STEP(CS##rbo, CS##rvo, CS##vvo, bfhi(wrd));                       \
    }

__global__ __launch_bounds__(128, 2) void k6_pass2(
    const float* __restrict__ qkv, const float* __restrict__ rel,
    const float* __restrict__ cq, const float* __restrict__ cs,
    const u16* __restrict__ qk,
    float* __restrict__ outraw, float* __restrict__ ostats)
{
    __shared__ __align__(16) u16 rbq[255 * 8];   // [d][ch0..7] qk-rel
    __shared__ __align__(16) u16 rvb[255 * 4];   // [d][4] v-rel, this half's ch
    __shared__ __align__(16) u16 vb[128 * 4];    // [j][4] v, this half's ch
    const int tid = threadIdx.x;                 // 0..127 = row i
    const int bid = blockIdx.x;
    const int half = bid & 1, g = (bid >> 1) & 15, n = bid >> 5;

    // stage rbq: 8 ch x 255 d  (rel rows 0..7)
#pragma unroll
    for (int k = 0; k < 16; ++k) {
        int f = tid + k * 128;          // < 2048
        int c = f >> 8, d = f & 255;
        if (d < 255) rbq[d * 8 + c] = f2bf(rel[c * 255 + d]);
    }
    // stage rvb: 4 ch x 255 d  (rel rows 8 + half*4 ..)
#pragma unroll
    for (int k = 0; k < 8; ++k) {
        int f = tid + k * 128;          // < 1024
        int c = f >> 8, d = f & 255;
        if (d < 255) rvb[d * 4 + c] = f2bf(rel[(8 + half * 4 + c) * 255 + d]);
    }
    // stage vb: 4 ch x 128 j (v normalized bf16), ch = half*4..+3
#pragma unroll
    for (int k = 0; k < 4; ++k) {
        int f = tid + k * 128;          // < 512
        int c = f >> 7, j = f & 127;
        int o = g * 16 + 8 + half * 4 + c;
        float v = fmaf(cq[o], qkv[((size_t)n * 256 + o) * 128 + j], cq[256 + o]);
        vb[j * 4 + c] = f2bf(v);
    }

    // log2e folded: exp(s) = exp2(s * log2e); all score terms scaled.
    const float LOG2E = 1.44269504f;
    const float aqk = cs[g] * LOG2E, aqe = cs[16 + g] * LOG2E, ake = cs[32 + g] * LOG2E;
    const int i = tid;

    // per-thread q/k: coalesced global loads (lane i -> address +i),
    // normalized + BN-sim scale (and log2e) folded. No LDS round-trip.
    const float* qb = qkv + ((size_t)n * 256 + g * 16) * 128 + i;
    float q0 = aqe * fmaf(cq[g*16+0], qb[0*128], cq[256+g*16+0]);
    float q1 = aqe * fmaf(cq[g*16+1], qb[1*128], cq[256+g*16+1]);
    float q2 = aqe * fmaf(cq[g*16+2], qb[2*128], cq[256+g*16+2]);
    float q3 = aqe * fmaf(cq[g*16+3], qb[3*128], cq[256+g*16+3]);
    float k0 = ake * fmaf(cq[g*16+4], qb[4*128], cq[256+g*16+4]);
    float k1 = ake * fmaf(cq[g*16+5], qb[5*128], cq[256+g*16+5]);
    float k2 = ake * fmaf(cq[g*16+6], qb[6*128], cq[256+g*16+6]);
    float k3 = ake * fmaf(cq[g*16+7], qb[7*128], cq[256+g*16+7]);

    // blocked qk: chunk jc at qkg + jc*2048 (u16 units)
    const u16* qkg = qk + (size_t)(n * 16 + g) * 16384 + i * 16;

    // issue jc=0's qk loads up front (overlap with barrier below)
    uint4 qA = *(const uint4*)(qkg);
    uint4 qB = *(const uint4*)(qkg + 8);

    __syncthreads();

    // per-thread LDS bases for the pipeline (compile-time offsets off these)
    const u16* prb = rbq + i * 8;
    const u16* prv = rvb + i * 4;

    // pipeline register sets
    bf16x8 Arbe, Arbo;  bf16x4 Arve, Arvo, Avve, Avvo;
    bf16x8 Brbe, Brbo;  bf16x4 Brve, Brvo, Bvve, Bvvo;

    K6_LOADU(A, 0);

    float l = 0.f;
    float am[4], ame[4];
#pragma unroll
    for (int c = 0; c < 4; ++c) { am[c] = 0.f; ame[c] = 0.f; }

#pragma unroll
    for (int jc = 0; jc < 8; ++jc) {
        // depth-1 global prefetch of jc+1's qk chunk (proven in v10/v14)
        uint4 nA, nB;
        if (jc < 7) {
            nA = *(const uint4*)(qkg + (size_t)(jc + 1) * 2048);
            nB = *(const uint4*)(qkg + (size_t)(jc + 1) * 2048 + 8);
        }

        K6_UNIT(A, B, jc * 8 + 0, qA.x);
        K6_UNIT(B, A, jc * 8 + 1, qA.y);
        K6_UNIT(A, B, jc * 8 + 2, qA.z);
        K6_UNIT(B, A, jc * 8 + 3, qA.w);
        K6_UNIT(A, B, jc * 8 + 4, qB.x);
        K6_UNIT(B, A, jc * 8 + 5, qB.y);
        K6_UNIT(A, B, jc * 8 + 6, qB.z);
        K6_UNIT(B, A, jc * 8 + 7, qB.w);

        if (jc < 7) { qA = nA; qB = nB; }
    }

    // epilogue: normalize, write this half's 8 output channels, BN stats
    float inv = 1.f / l;
    float o8[8];
#pragma unroll
    for (int c = 0; c < 4; ++c) { o8[2 * c] = am[c] * inv; o8[2 * c + 1] = ame[c] * inv; }

    float* orow = outraw + ((size_t)n * 256 + g * 16 + half * 8) * 128 + i;
#pragma unroll
    for (int c8 = 0; c8 < 8; ++c8) orow[c8 * 128] = o8[c8];

    const int lane = tid & 63;
#pragma unroll
    for (int c8 = 0; c8 < 8; ++c8) {
        float sv = o8[c8], sq = o8[c8] * o8[c8];
#pragma unroll
        for (int mm = 1; mm < 64; mm <<= 1) { sv += __shfl_xor(sv, mm); sq += __shfl_xor(sq, mm); }
        if (lane == 0) {
            atomicAdd(&ostats[g * 16 + half * 8 + c8], sv);
            atomicAdd(&ostats[256 + g * 16 + half * 8 + c8], sq);
        }
    }
}

__global__ void k7_coef_out(const float* __restrict__ stats,
                            const float* __restrict__ gamma, const float* __restrict__ beta,
                            float* __restrict__ coef)
{
    int o = threadIdx.x;
    const float cnt = 16384.f;
    float mean = stats[608 + o] / cnt;
    float var  = stats[864 + o] / cnt - mean * mean;
    float a = gamma[o] * rsqrtf(var + EPS);
    coef[o] = a;
    coef[256 + o] = beta[o] - a * mean;
}

__global__ __launch_bounds__(256) void k8_final(
    const float* __restrict__ outraw, const float* __restrict__ co,
    float* __restrict__ out)
{
    int idx = blockIdx.x * 256 + threadIdx.x;
    int w  = idx & 127;
    int h  = (idx >> 7) & 63;
    int oc = (idx >> 13) & 127;
    int b  = idx >> 20;
    int n  = b * 64 + h;
    int o0 = oc * 2;
    float x0 = outraw[((size_t)n * 256 + o0) * 128 + w];
    float x1 = outraw[((size_t)n * 256 + o0 + 1) * 128 + w];
    out[idx] = (co[o0] * x0 + co[256 + o0]) + (co[o0 + 1] * x1 + co[256 + o0 + 1]);
}

// ============================================================
// Workspace layout (floats): unchanged from round 0.
// ============================================================
extern "C" void kernel_launch(void* const* d_in, const int* in_sizes, int n_in,
                              void* d_out, int out_size, void* d_ws, size_t ws_size,
                              hipStream_t stream)
{
    const float* x   = (const float*)d_in[0];
    const float* Wq  = (const float*)d_in[1];
    const float* gq  = (const float*)d_in[2];
    const float* bq  = (const float*)d_in[3];
    const float* rel = (const float*)d_in[4];
    const float* gs  = (const float*)d_in[5];
    const float* bs  = (const float*)d_in[6];
    const float* go  = (const float*)d_in[7];
    const float* bo  = (const float*)d_in[8];

    float* ws     = (float*)d_ws;
    float* qkv    = ws;
    float* outraw = ws + 4194304;
    u16*   qk     = (u16*)(ws + 8388608);
    float* stats  = ws + 25165824;
    float* cq     = stats + 1120;
    float* cs     = stats + 1632;
    float* co     = stats + 1728;

    (void)hipMemsetAsync(stats, 0, 1120 * sizeof(float), stream);

    k1_gemm_qkv<<<dim3(4, 128), 256, 0, stream>>>(x, Wq, qkv, stats);
    k3_coef_qkv<<<1, 256, 0, stream>>>(stats, gq, bq, cq);
    k4_pass1<<<2048, 512, 0, stream>>>(qkv, rel, cq, qk, stats);
    k5_coef_sim<<<1, 64, 0, stream>>>(stats, gs, bs, cs);
    k6_pass2<<<4096, 128, 0, stream>>>(qkv, rel, cq, cs, qk, outraw, stats + 608);
    k7_coef_out<<<1, 256, 0, stream>>>(stats, go, bo, co);
    k8_final<<<8192, 256, 0, stream>>>(outraw, co, (float*)d_out);
}

// Round 10
// 316.810 us; speedup vs baseline: 1.0597x; 1.0597x over previous
//
#include <hip/hip_runtime.h>

#define EPS 1e-5f
typedef unsigned short u16;
typedef unsigned int u32;

typedef __attribute__((ext_vector_type(8))) short bf16x8;
typedef __attribute__((ext_vector_type(4))) short bf16x4;
typedef __attribute__((ext_vector_type(4))) float f32x4;
typedef __attribute__((ext_vector_type(2))) float f32x2;

// function, NOT macro: braced-init f32x2 args contain commas which
// break macro argument parsing (round-9 compile failure).
__device__ __forceinline__ f32x2 fma2(f32x2 a, f32x2 b, f32x2 c) {
    return __builtin_elementwise_fma(a, b, c);
}

// ---------- bf16 helpers ----------
__device__ __forceinline__ float bf2f(u16 h) {
    u32 u = ((u32)h) << 16;
    return __builtin_bit_cast(float, u);
}
__device__ __forceinline__ u16 f2bf(float f) {
    u32 u = __builtin_bit_cast(u32, f);
    u32 r = (u + 0x7fffu + ((u >> 16) & 1u)) >> 16;   // RNE
    return (u16)r;
}
__device__ __forceinline__ u32 pack2(float a, float b) {
    return (u32)f2bf(a) | ((u32)f2bf(b) << 16);
}
// extract packed bf16 pair from a u32 word, pure register bit-ops
__device__ __forceinline__ float bflo(u32 u) {
    return __builtin_bit_cast(float, u << 16);
}
__device__ __forceinline__ float bfhi(u32 u) {
    return __builtin_bit_cast(float, u & 0xffff0000u);
}
// packed pair {lo, hi} from one u32 of 2 bf16
__device__ __forceinline__ f32x2 bfpair(u32 u) {
    f32x2 r;
    r.x = bflo(u);
    r.y = bfhi(u);
    return r;
}

// ============================================================
// K1: qkv[n,o,l] = sum_c W[o,c] * x[b,c,h,l]   (n = b*64+h)
// ============================================================
__global__ __launch_bounds__(256) void k1_gemm_qkv(
    const float* __restrict__ x, const float* __restrict__ Wq,
    float* __restrict__ qkv, float* __restrict__ stats)
{
    __shared__ float Wt[64 * 68];
    __shared__ float xt[64 * 128];
    const int tid = threadIdx.x;
    const int ot = blockIdx.x;
    const int n  = blockIdx.y;
    const int b = n >> 6, h = n & 63;
    const int to = tid >> 5, tl = tid & 31;
    const int o0 = to * 8, l0 = tl * 4;

    float acc[8][4];
#pragma unroll
    for (int r = 0; r < 8; ++r) { acc[r][0]=0.f; acc[r][1]=0.f; acc[r][2]=0.f; acc[r][3]=0.f; }

    for (int cb = 0; cb < 128; cb += 64) {
        __syncthreads();
#pragma unroll
        for (int k = 0; k < 4; ++k) {
            int f = tid + k * 256;
            int oo = f >> 4, c4 = f & 15;
            float4 v = *(const float4*)(Wq + (ot * 64 + oo) * 128 + cb + c4 * 4);
            *(float4*)(Wt + oo * 68 + c4 * 4) = v;
        }
#pragma unroll
        for (int k = 0; k < 8; ++k) {
            int f = tid + k * 256;
            int c = f >> 5, l4 = f & 31;
            float4 v = *(const float4*)(x + ((size_t)((b * 128 + cb + c) * 64 + h)) * 128 + l4 * 4);
            *(float4*)(xt + c * 128 + l4 * 4) = v;
        }
        __syncthreads();
#pragma unroll 4
        for (int c = 0; c < 64; ++c) {
            float4 xv = *(const float4*)(xt + c * 128 + l0);
#pragma unroll
            for (int r = 0; r < 8; ++r) {
                float w = Wt[(o0 + r) * 68 + c];
                acc[r][0] += w * xv.x; acc[r][1] += w * xv.y;
                acc[r][2] += w * xv.z; acc[r][3] += w * xv.w;
            }
        }
    }

#pragma unroll
    for (int r = 0; r < 8; ++r) {
        int o = ot * 64 + o0 + r;
        *(float4*)(qkv + ((size_t)n * 256 + o) * 128 + l0) =
            make_float4(acc[r][0], acc[r][1], acc[r][2], acc[r][3]);
        float s  = acc[r][0] + acc[r][1] + acc[r][2] + acc[r][3];
        float sq = acc[r][0]*acc[r][0] + acc[r][1]*acc[r][1] + acc[r][2]*acc[r][2] + acc[r][3]*acc[r][3];
#pragma unroll
        for (int m = 1; m < 32; m <<= 1) {
            s  += __shfl_xor(s, m);
            sq += __shfl_xor(sq, m);
        }
        if (tl == 0) {
            atomicAdd(&stats[o], s);
            atomicAdd(&stats[256 + o], sq);
        }
    }
}

__global__ void k3_coef_qkv(const float* __restrict__ stats,
                            const float* __restrict__ gamma, const float* __restrict__ beta,
                            float* __restrict__ coef)
{
    int o = threadIdx.x;
    const float cnt = 16384.f;
    float mean = stats[o] / cnt;
    float var  = stats[256 + o] / cnt - mean * mean;
    float a = gamma[o] * rsqrtf(var + EPS);
    coef[o] = a;
    coef[256 + o] = beta[o] - a * mean;
}

// ============================================================
// K4 v3 (pass 1): unchanged compute. Writer epilogue: qk stored
// in [jc][row][16] blocks (jc = 16-col chunk) so K6's per-jc wave
// read is a contiguous span.
// ============================================================
__global__ __launch_bounds__(512, 4) void k4_pass1(
    const float* __restrict__ qkv, const float* __restrict__ rel,
    const float* __restrict__ cq, u16* __restrict__ qk,
    float* __restrict__ stats)
{
    __shared__ u16 QEb[128 * 136];
    __shared__ u16 KEb[128 * 136];
    __shared__ float red[8 * 6];
    const int tid = threadIdx.x;
    const int n = blockIdx.x >> 4, g = blockIdx.x & 15;

    const int pt = tid & 31, pi = tid >> 5;
    const int t0 = pt * 4, i0 = pi * 8;
    const int d0 = t0 - i0 + 120;

    float qes = 0.f, qesq = 0.f, kes = 0.f, kesq = 0.f;

#pragma unroll
    for (int mat = 0; mat < 2; ++mat) {
        float qv[4][4];
#pragma unroll
        for (int c = 0; c < 4; ++c) {
            int o = g * 16 + mat * 4 + c;
            float a = cq[o], bb = cq[256 + o];
            float4 x0 = *(const float4*)(qkv + ((size_t)n * 256 + o) * 128 + t0);
            qv[c][0] = fmaf(a, x0.x, bb); qv[c][1] = fmaf(a, x0.y, bb);
            qv[c][2] = fmaf(a, x0.z, bb); qv[c][3] = fmaf(a, x0.w, bb);
        }
        float rr[4][12];
#pragma unroll
        for (int c = 0; c < 4; ++c) {
            const float* p = rel + (mat * 4 + c) * 255 + d0;
#pragma unroll
            for (int j = 0; j < 3; ++j) {
                float4 v = *(const float4*)(p + j * 4);
                rr[c][j*4+0] = v.x; rr[c][j*4+1] = v.y;
                rr[c][j*4+2] = v.z; rr[c][j*4+3] = v.w;
            }
        }
        u16* MB = mat ? KEb : QEb;
        float s = 0.f, sq = 0.f;
#pragma unroll
        for (int ii = 0; ii < 8; ++ii) {
            float vv[4];
#pragma unroll
            for (int tt = 0; tt < 4; ++tt) {
                int dl = tt - ii + 7;
                float v = qv[0][tt] * rr[0][dl] + qv[1][tt] * rr[1][dl]
                        + qv[2][tt] * rr[2][dl] + qv[3][tt] * rr[3][dl];
                vv[tt] = v;
                s += v; sq = fmaf(v, v, sq);
            }
            *(uint2*)(MB + (i0 + ii) * 136 + t0) =
                make_uint2(pack2(vv[0], vv[1]), pack2(vv[2], vv[3]));
        }
        if (mat == 0) { qes = s; qesq = sq; } else { kes = s; kesq = sq; }
    }
    __syncthreads();

    const int lane = tid & 63, wv = tid >> 6;
    const int fm = lane & 15, fq = lane >> 4;

    f32x4 acc[8];
#pragma unroll
    for (int tj = 0; tj < 8; ++tj) acc[tj] = (f32x4){0.f, 0.f, 0.f, 0.f};

#pragma unroll
    for (int kb = 0; kb < 4; ++kb) {
        const int ko = kb * 32 + fq * 8;
        bf16x8 a0 = *(const bf16x8*)(QEb + (wv * 16 + fm) * 136 + ko);
#pragma unroll
        for (int tj = 0; tj < 8; ++tj) {
            bf16x8 bfr = *(const bf16x8*)(KEb + (tj * 16 + fm) * 136 + ko);
            acc[tj] = __builtin_amdgcn_mfma_f32_16x16x32_bf16(a0, bfr, acc[tj], 0, 0, 0);
        }
    }

    float qks = 0.f, qksq = 0.f;
#pragma unroll
    for (int tj = 0; tj < 8; ++tj) {
#pragma unroll
        for (int r = 0; r < 4; ++r) {
            float v = acc[tj][r];
            qks += v; qksq = fmaf(v, v, qksq);
            QEb[(wv * 16 + fq * 4 + r) * 136 + tj * 16 + fm] = f2bf(v);
        }
    }

#pragma unroll
    for (int m = 1; m < 64; m <<= 1) {
        qes += __shfl_xor(qes, m);  qesq += __shfl_xor(qesq, m);
        kes += __shfl_xor(kes, m);  kesq += __shfl_xor(kesq, m);
        qks += __shfl_xor(qks, m);  qksq += __shfl_xor(qksq, m);
    }
    if (lane == 0) {
        red[wv * 6 + 0] = qes; red[wv * 6 + 1] = qesq;
        red[wv * 6 + 2] = kes; red[wv * 6 + 3] = kesq;
        red[wv * 6 + 4] = qks; red[wv * 6 + 5] = qksq;
    }
    __syncthreads();

    u16* qkg = qk + (size_t)(n * 16 + g) * 16384;
#pragma unroll
    for (int k = 0; k < 4; ++k) {
        int f = tid + k * 512;
        int row = f >> 4, c8 = f & 15;
        uint4 v = *(const uint4*)(QEb + row * 136 + c8 * 8);
        *(uint4*)(qkg + ((c8 >> 1) * 128 + row) * 16 + (c8 & 1) * 8) = v;
    }

    if (tid < 6) {
        float tot = 0.f;
#pragma unroll
        for (int w = 0; w < 8; ++w) tot += red[w * 6 + tid];
        int off = (tid & 1) ? 560 : 512;
        int ch = (tid < 2) ? (16 + g) : (tid < 4) ? (32 + g) : g;
        atomicAdd(&stats[off + ch], tot);
    }
}

__global__ void k5_coef_sim(const float* __restrict__ stats,
                            const float* __restrict__ gamma, const float* __restrict__ beta,
                            float* __restrict__ coef)
{
    int ch = threadIdx.x;
    if (ch < 48) {
        const float cnt = 2097152.f;
        float mean = stats[512 + ch] / cnt;
        float var  = stats[560 + ch] / cnt - mean * mean;
        float a = gamma[ch] * rsqrtf(var + EPS);
        coef[ch] = a;
        coef[48 + ch] = beta[ch] - a * mean;
    }
}

// ============================================================
// K6 v17b (pass 2): v15 STRUCTURE VERBATIM (140us proven) +
// PACKED FP32 ARITHMETIC (v_pk_fma_f32 via f32x2
// __builtin_elementwise_fma) + exp2f/log2e fold.
// Round-9 was a macro/braced-init compile failure; fma2 is now a
// function. Score dot: 4 pk-fma + hadd (was 8 fma); accumulate:
// 4 pk-fma (was 8 fma). ~46 -> ~32 issue slots/step. No new
// cross-step live state -> no regalloc provocation.
// Diagnostics: VGPR 28-48, FETCH ~78MB / WRITE ~20MB, no _ord-0
// anomaly. If dur flat: clang scalarized -> revert packing.
// ============================================================
#define K6_STEP(rbw, rvw, vvw, qkf)                                          \
    {                                                                        \
        f32x2 sa0; sa0.x = aqk * (qkf); sa0.y = 0.f;                         \
        f32x2 sa = fma2(q01, bfpair(rbw.x), sa0);                            \
        sa = fma2(q23,  bfpair(rbw.y), sa);                                  \
        sa = fma2(k01v, bfpair(rbw.z), sa);                                  \
        sa = fma2(k23v, bfpair(rbw.w), sa);                                  \
        float e = exp2f(sa.x + sa.y);                                        \
        l += e;                                                              \
        f32x2 e2; e2.x = e; e2.y = e;                                        \
        am01  = fma2(e2, bfpair(vvw.x), am01);                               \
        am23  = fma2(e2, bfpair(vvw.y), am23);                               \
        ame01 = fma2(e2, bfpair(rvw.x), ame01);                              \
        ame23 = fma2(e2, bfpair(rvw.y), ame23);                              \
    }

// one js group: 4 steps; rb from rbq (16B rows), rv from rvb (8B rows),
// vv from vb (8B rows, wave-uniform j -> broadcast)
#define K6_JS(ddv, jjv, w0, w1)                                              \
    {                                                                        \
        const int dd = (ddv); const int jj = (jjv);                          \
        uint4 rb0 = *(const uint4*)(rbq + (dd    ) * 8);                     \
        uint4 rb1 = *(const uint4*)(rbq + (dd - 1) * 8);                     \
        uint4 rb2 = *(const uint4*)(rbq + (dd - 2) * 8);                     \
        uint4 rb3 = *(const uint4*)(rbq + (dd - 3) * 8);                     \
        uint2 rv0 = *(const uint2*)(rvb + (dd    ) * 4);                     \
        uint2 rv1 = *(const uint2*)(rvb + (dd - 1) * 4);                     \
        uint2 rv2 = *(const uint2*)(rvb + (dd - 2) * 4);                     \
        uint2 rv3 = *(const uint2*)(rvb + (dd - 3) * 4);                     \
        uint2 vv0 = *(const uint2*)(vb + (jj + 0) * 4);                      \
        uint2 vv1 = *(const uint2*)(vb + (jj + 1) * 4);                      \
        uint2 vv2 = *(const uint2*)(vb + (jj + 2) * 4);                      \
        uint2 vv3 = *(const uint2*)(vb + (jj + 3) * 4);                      \
        K6_STEP(rb0, rv0, vv0, bflo(w0));                                    \
        K6_STEP(rb1, rv1, vv1, bfhi(w0));                                    \
        K6_STEP(rb2, rv2, vv2, bflo(w1));                                    \
        K6_STEP(rb3, rv3, vv3, bfhi(w1));                                    \
    }

__global__ __launch_bounds__(128, 2) void k6_pass2(
    const float* __restrict__ qkv, const float* __restrict__ rel,
    const float* __restrict__ cq, const float* __restrict__ cs,
    const u16* __restrict__ qk,
    float* __restrict__ outraw, float* __restrict__ ostats)
{
    __shared__ __align__(16) u16 rbq[255 * 8];   // [d][ch0..7] qk-rel
    __shared__ __align__(16) u16 rvb[255 * 4];   // [d][4] v-rel, this half's ch
    __shared__ __align__(16) u16 vb[128 * 4];    // [j][4] v, this half's ch
    const int tid = threadIdx.x;                 // 0..127 = row i
    const int bid = blockIdx.x;
    const int half = bid & 1, g = (bid >> 1) & 15, n = bid >> 5;

    // stage rbq: 8 ch x 255 d  (rel rows 0..7)
#pragma unroll
    for (int k = 0; k < 16; ++k) {
        int f = tid + k * 128;          // < 2048
        int c = f >> 8, d = f & 255;
        if (d < 255) rbq[d * 8 + c] = f2bf(rel[c * 255 + d]);
    }
    // stage rvb: 4 ch x 255 d  (rel rows 8 + half*4 ..)
#pragma unroll
    for (int k = 0; k < 8; ++k) {
        int f = tid + k * 128;          // < 1024
        int c = f >> 8, d = f & 255;
        if (d < 255) rvb[d * 4 + c] = f2bf(rel[(8 + half * 4 + c) * 255 + d]);
    }
    // stage vb: 4 ch x 128 j (v normalized bf16), ch = half*4..+3
#pragma unroll
    for (int k = 0; k < 4; ++k) {
        int f = tid + k * 128;          // < 512
        int c = f >> 7, j = f & 127;
        int o = g * 16 + 8 + half * 4 + c;
        float v = fmaf(cq[o], qkv[((size_t)n * 256 + o) * 128 + j], cq[256 + o]);
        vb[j * 4 + c] = f2bf(v);
    }

    // log2e folded into all score scales: exp(s) = exp2(s*log2e)
    const float LOG2E = 1.44269504f;
    const float aqk = cs[g] * LOG2E, aqe = cs[16 + g] * LOG2E, ake = cs[32 + g] * LOG2E;
    const int i = tid;

    // per-thread q/k: coalesced global loads (lane i -> address +i),
    // normalized + BN-sim scale (and log2e) folded. Packed as f32x2.
    const float* qb = qkv + ((size_t)n * 256 + g * 16) * 128 + i;
    f32x2 q01, q23, k01v, k23v;
    q01.x = aqe * fmaf(cq[g*16+0], qb[0*128], cq[256+g*16+0]);
    q01.y = aqe * fmaf(cq[g*16+1], qb[1*128], cq[256+g*16+1]);
    q23.x = aqe * fmaf(cq[g*16+2], qb[2*128], cq[256+g*16+2]);
    q23.y = aqe * fmaf(cq[g*16+3], qb[3*128], cq[256+g*16+3]);
    k01v.x = ake * fmaf(cq[g*16+4], qb[4*128], cq[256+g*16+4]);
    k01v.y = ake * fmaf(cq[g*16+5], qb[5*128], cq[256+g*16+5]);
    k23v.x = ake * fmaf(cq[g*16+6], qb[6*128], cq[256+g*16+6]);
    k23v.y = ake * fmaf(cq[g*16+7], qb[7*128], cq[256+g*16+7]);

    // blocked qk: chunk jc at qkg + jc*2048 (u16 units)
    const u16* qkg = qk + (size_t)(n * 16 + g) * 16384 + i * 16;

    // issue jc=0's loads up front (overlap with the barrier below)
    uint4 qA = *(const uint4*)(qkg);
    uint4 qB = *(const uint4*)(qkg + 8);

    __syncthreads();

    float l = 0.f;
    f32x2 am01, am23, ame01, ame23;
    am01.x = 0.f; am01.y = 0.f; am23.x = 0.f; am23.y = 0.f;
    ame01.x = 0.f; ame01.y = 0.f; ame23.x = 0.f; ame23.y = 0.f;

#pragma unroll
    for (int jc = 0; jc < 8; ++jc) {
        // depth-1 prefetch of next chunk (proven clean in v10/v14/v15)
        uint4 nA, nB;
        if (jc < 7) {
            nA = *(const uint4*)(qkg + (size_t)(jc + 1) * 2048);
            nB = *(const uint4*)(qkg + (size_t)(jc + 1) * 2048 + 8);
        }

        const int dbase = i + 127 - jc * 16;
        const int jb = jc * 16;
        K6_JS(dbase,      jb,      qA.x, qA.y);
        K6_JS(dbase - 4,  jb + 4,  qA.z, qA.w);
        K6_JS(dbase - 8,  jb + 8,  qB.x, qB.y);
        K6_JS(dbase - 12, jb + 12, qB.z, qB.w);

        if (jc < 7) { qA = nA; qB = nB; }
    }

    // epilogue: normalize, write this half's 8 output channels, BN stats
    float inv = 1.f / l;
    float am[4] = {am01.x, am01.y, am23.x, am23.y};
    float ame[4] = {ame01.x, ame01.y, ame23.x, ame23.y};
    float o8[8];
#pragma unroll
    for (int c = 0; c < 4; ++c) { o8[2 * c] = am[c] * inv; o8[2 * c + 1] = ame[c] * inv; }

    float* orow = outraw + ((size_t)n * 256 + g * 16 + half * 8) * 128 + i;
#pragma unroll
    for (int c8 = 0; c8 < 8; ++c8) orow[c8 * 128] = o8[c8];

    const int lane = tid & 63;
#pragma unroll
    for (int c8 = 0; c8 < 8; ++c8) {
        float sv = o8[c8], sq = o8[c8] * o8[c8];
#pragma unroll
        for (int mm = 1; mm < 64; mm <<= 1) { sv += __shfl_xor(sv, mm); sq += __shfl_xor(sq, mm); }
        if (lane == 0) {
            atomicAdd(&ostats[g * 16 + half * 8 + c8], sv);
            atomicAdd(&ostats[256 + g * 16 + half * 8 + c8], sq);
        }
    }
}

__global__ void k7_coef_out(const float* __restrict__ stats,
                            const float* __restrict__ gamma, const float* __restrict__ beta,
                            float* __restrict__ coef)
{
    int o = threadIdx.x;
    const float cnt = 16384.f;
    float mean = stats[608 + o] / cnt;
    float var  = stats[864 + o] / cnt - mean * mean;
    float a = gamma[o] * rsqrtf(var + EPS);
    coef[o] = a;
    coef[256 + o] = beta[o] - a * mean;
}

__global__ __launch_bounds__(256) void k8_final(
    const float* __restrict__ outraw, const float* __restrict__ co,
    float* __restrict__ out)
{
    int idx = blockIdx.x * 256 + threadIdx.x;
    int w  = idx & 127;
    int h  = (idx >> 7) & 63;
    int oc = (idx >> 13) & 127;
    int b  = idx >> 20;
    int n  = b * 64 + h;
    int o0 = oc * 2;
    float x0 = outraw[((size_t)n * 256 + o0) * 128 + w];
    float x1 = outraw[((size_t)n * 256 + o0 + 1) * 128 + w];
    out[idx] = (co[o0] * x0 + co[256 + o0]) + (co[o0 + 1] * x1 + co[256 + o0 + 1]);
}

// ============================================================
// Workspace layout (floats): unchanged from round 0.
// ============================================================
extern "C" void kernel_launch(void* const* d_in, const int* in_sizes, int n_in,
                              void* d_out, int out_size, void* d_ws, size_t ws_size,
                              hipStream_t stream)
{
    const float* x   = (const float*)d_in[0];
    const float* Wq  = (const float*)d_in[1];
    const float* gq  = (const float*)d_in[2];
    const float* bq  = (const float*)d_in[3];
    const float* rel = (const float*)d_in[4];
    const float* gs  = (const float*)d_in[5];
    const float* bs  = (const float*)d_in[6];
    const float* go  = (const float*)d_in[7];
    const float* bo  = (const float*)d_in[8];

    float* ws     = (float*)d_ws;
    float* qkv    = ws;
    float* outraw = ws + 4194304;
    u16*   qk     = (u16*)(ws + 8388608);
    float* stats  = ws + 25165824;
    float* cq     = stats + 1120;
    float* cs     = stats + 1632;
    float* co     = stats + 1728;

    (void)hipMemsetAsync(stats, 0, 1120 * sizeof(float), stream);

    k1_gemm_qkv<<<dim3(4, 128), 256, 0, stream>>>(x, Wq, qkv, stats);
    k3_coef_qkv<<<1, 256, 0, stream>>>(stats, gq, bq, cq);
    k4_pass1<<<2048, 512, 0, stream>>>(qkv, rel, cq, qk, stats);
    k5_coef_sim<<<1, 64, 0, stream>>>(stats, gs, bs, cs);
    k6_pass2<<<4096, 128, 0, stream>>>(qkv, rel, cq, cs, qk, outraw, stats + 608);
    k7_coef_out<<<1, 256, 0, stream>>>(stats, go, bo, co);
    k8_final<<<8192, 256, 0, stream>>>(outraw, co, (float*)d_out);
}